// Round 1
// baseline (516.872 us; speedup 1.0000x reference)
//
#include <hip/hip_runtime.h>

#define T_TOK 4096
#define DDIM 1024
#define FDIM 4096
#define NE 8
#define NPAIR 8192

typedef short bf16x8 __attribute__((ext_vector_type(8)));
typedef float f32x4 __attribute__((ext_vector_type(4)));

__device__ inline unsigned short f2bf(float f) {
  union { float f; unsigned u; } a; a.f = f;
  unsigned r = a.u + 0x7fffu + ((a.u >> 16) & 1u);
  return (unsigned short)(r >> 16);
}

// ---------------- router: 1 wave per token ----------------
__global__ __launch_bounds__(256) void router_kernel(
    const float* __restrict__ x, const float* __restrict__ noise,
    const float* __restrict__ Wr, const float* __restrict__ br,
    const float* __restrict__ Wn, const float* __restrict__ bn,
    int* __restrict__ tok_top, float* __restrict__ tok_gate, int* __restrict__ cnt)
{
  int t = blockIdx.x * 4 + (threadIdx.x >> 6);
  int lane = threadIdx.x & 63;
  const float* xr = x + (size_t)t * DDIM;
  float accR[NE] = {}, accN[NE] = {};
  for (int d = lane; d < DDIM; d += 64) {
    float xv = xr[d];
    const float* wr = Wr + (size_t)d * NE;
    const float* wn = Wn + (size_t)d * NE;
#pragma unroll
    for (int e = 0; e < NE; ++e) {
      accR[e] = fmaf(xv, wr[e], accR[e]);
      accN[e] = fmaf(xv, wn[e], accN[e]);
    }
  }
#pragma unroll
  for (int off = 32; off > 0; off >>= 1) {
#pragma unroll
    for (int e = 0; e < NE; ++e) {
      accR[e] += __shfl_xor(accR[e], off);
      accN[e] += __shfl_xor(accN[e], off);
    }
  }
  if (lane == 0) {
    float noisy[NE];
#pragma unroll
    for (int e = 0; e < NE; ++e) {
      float lg = accR[e] + br[e];
      float nl = accN[e] + bn[e];
      float sp = fmaxf(nl, 0.f) + log1pf(expf(-fabsf(nl)));
      noisy[e] = lg + noise[(size_t)t * NE + e] * sp;
    }
    int e0 = 0;
#pragma unroll
    for (int e = 1; e < NE; ++e) if (noisy[e] > noisy[e0]) e0 = e;
    int e1 = (e0 == 0) ? 1 : 0;
#pragma unroll
    for (int e = 0; e < NE; ++e)
      if (e != e0 && e != e1 && noisy[e] > noisy[e1]) e1 = e;
    float v0 = noisy[e0], v1 = noisy[e1];
    float ex = __expf(v1 - v0);
    float inv = 1.f / (1.f + ex);
    tok_top[t * 2] = e0; tok_top[t * 2 + 1] = e1;
    tok_gate[t * 2] = inv; tok_gate[t * 2 + 1] = ex * inv;
    atomicAdd(&cnt[e0], 1);
    atomicAdd(&cnt[e1], 1);
  }
}

// ---------------- scan ----------------
__global__ void scan_kernel(const int* __restrict__ cnt, int* __restrict__ off,
                            int* __restrict__ cur)
{
  if (threadIdx.x == 0) {
    int s = 0;
    for (int e = 0; e < NE; ++e) { off[e] = s; cur[e] = s; s += cnt[e]; }
    off[NE] = s;
  }
}

// ---------------- scatter ----------------
__global__ __launch_bounds__(256) void scatter_kernel(
    const int* __restrict__ tok_top, const float* __restrict__ tok_gate,
    int* __restrict__ cur, int* __restrict__ pair_tok, int* __restrict__ tok_ppos)
{
  int t = blockIdx.x * 256 + threadIdx.x;
  if (t >= T_TOK) return;
  for (int k = 0; k < 2; ++k) {
    int e = tok_top[t * 2 + k];
    int pos = atomicAdd(&cur[e], 1);
    pair_tok[pos] = t;
    tok_ppos[t * 2 + k] = pos;
  }
}

// ---------------- gather x rows -> bf16, grouped by expert ----------------
__global__ __launch_bounds__(256) void gather_x_kernel(
    const float* __restrict__ x, const int* __restrict__ pair_tok,
    ushort* __restrict__ xg)
{
  int p = blockIdx.x;
  int t = pair_tok[p];
  int tid = threadIdx.x;
  float4 v = ((const float4*)(x + (size_t)t * DDIM))[tid];
  ushort4 o;
  o.x = f2bf(v.x); o.y = f2bf(v.y); o.z = f2bf(v.z); o.w = f2bf(v.w);
  ((ushort4*)(xg + (size_t)p * DDIM))[tid] = o;
}

// ---------------- transpose + f32->bf16: src[E][R][C] -> dst[E][C][R] ----------------
__global__ __launch_bounds__(256) void transpose_bf_kernel(
    const float* __restrict__ src, ushort* __restrict__ dst, int R, int C)
{
  __shared__ float tile[32][33];
  int e = blockIdx.z;
  int c0 = blockIdx.x * 32;
  int r0 = blockIdx.y * 32;
  int cl = threadIdx.x & 31;
  int rl = threadIdx.x >> 5;  // 0..7
  const float* s = src + (size_t)e * R * C;
#pragma unroll
  for (int rr = 0; rr < 32; rr += 8)
    tile[rr + rl][cl] = s[(size_t)(r0 + rr + rl) * C + c0 + cl];
  __syncthreads();
  ushort* d = dst + (size_t)e * C * R;
#pragma unroll
  for (int rr = 0; rr < 32; rr += 8) {
    int cr = rr + rl;
    d[(size_t)(c0 + cr) * R + r0 + cl] = f2bf(tile[cl][cr]);
  }
}

// ---------------- grouped GEMM: C[M][N] = A[M][KD] * BT[N][KD]^T ----------------
// EPI==0: Hout = relu(C + bias) as bf16   EPI==1: EOout = C + bias as f32
template<int KD, int NTX, int EPI>
__global__ __launch_bounds__(256) void gemm_kernel(
    const ushort* __restrict__ A, const ushort* __restrict__ BT,
    const int* __restrict__ off, const float* __restrict__ bias,
    ushort* __restrict__ Hout, float* __restrict__ EOout)
{
  constexpr int N = NTX * 128;
  int e = blockIdx.y >> 6;
  int bm = blockIdx.y & 63;
  int base = off[e];
  int cnt = off[e + 1] - base;
  if (bm * 128 >= cnt) return;
  int n0 = blockIdx.x * 128;
  int tid = threadIdx.x;
  int lane = tid & 63;
  int wid = tid >> 6;
  int wr = wid >> 1, wc = wid & 1;

  __shared__ __align__(16) ushort As[128][32];
  __shared__ __align__(16) ushort Bs[128][32];

  const ushort* Ag = A + (size_t)(base + bm * 128) * KD;
  const ushort* Bg = BT + ((size_t)e * N + n0) * KD;

  f32x4 acc[4][4] = {};

  for (int k0 = 0; k0 < KD; k0 += 32) {
#pragma unroll
    for (int c = 0; c < 2; ++c) {
      int j = tid + c * 256;
      int r = j >> 2;             // 0..127
      int kc = (j & 3) * 8;       // bf16 col offset
      uint4 va = *(const uint4*)(Ag + (size_t)r * KD + k0 + kc);
      uint4 vb = *(const uint4*)(Bg + (size_t)r * KD + k0 + kc);
      int bofs = (r * 64 + kc * 2) ^ ((r & 7) << 4);  // XOR swizzle
      *(uint4*)((char*)As + bofs) = va;
      *(uint4*)((char*)Bs + bofs) = vb;
    }
    __syncthreads();
    bf16x8 af[4], bv[4];
#pragma unroll
    for (int m = 0; m < 4; ++m) {
      int row = wr * 64 + m * 16 + (lane & 15);
      int bofs = (row * 64 + (lane >> 4) * 16) ^ ((row & 7) << 4);
      af[m] = *(const bf16x8*)((const char*)As + bofs);
    }
#pragma unroll
    for (int n = 0; n < 4; ++n) {
      int row = wc * 64 + n * 16 + (lane & 15);
      int bofs = (row * 64 + (lane >> 4) * 16) ^ ((row & 7) << 4);
      bv[n] = *(const bf16x8*)((const char*)Bs + bofs);
    }
#pragma unroll
    for (int m = 0; m < 4; ++m)
#pragma unroll
      for (int n = 0; n < 4; ++n)
        acc[m][n] = __builtin_amdgcn_mfma_f32_16x16x32_bf16(af[m], bv[n], acc[m][n], 0, 0, 0);
    __syncthreads();
  }

  // epilogue: C row = wr*64+m*16+(lane>>4)*4+q ; col = wc*64+n*16+(lane&15)
  int rq = (lane >> 4) << 2;
#pragma unroll
  for (int m = 0; m < 4; ++m) {
#pragma unroll
    for (int q = 0; q < 4; ++q) {
      int r = bm * 128 + wr * 64 + m * 16 + rq + q;
      if (r < cnt) {
#pragma unroll
        for (int n = 0; n < 4; ++n) {
          int col = n0 + wc * 64 + n * 16 + (lane & 15);
          float v = acc[m][n][q] + bias[(size_t)e * N + col];
          if (EPI == 0) {
            v = fmaxf(v, 0.f);
            Hout[(size_t)(base + r) * FDIM + col] = f2bf(v);
          } else {
            EOout[(size_t)(base + r) * DDIM + col] = v;
          }
        }
      }
    }
  }
}

// ---------------- combine: out[t] = g0*eo[p0] + g1*eo[p1] ----------------
__global__ __launch_bounds__(256) void combine_kernel(
    const float* __restrict__ eo, const int* __restrict__ tok_ppos,
    const float* __restrict__ tok_gate, float* __restrict__ out)
{
  int t = blockIdx.x;
  int tid = threadIdx.x;
  int p0 = tok_ppos[t * 2], p1 = tok_ppos[t * 2 + 1];
  float g0 = tok_gate[t * 2], g1 = tok_gate[t * 2 + 1];
  float4 a = ((const float4*)(eo + (size_t)p0 * DDIM))[tid];
  float4 b = ((const float4*)(eo + (size_t)p1 * DDIM))[tid];
  float4 o;
  o.x = g0 * a.x + g1 * b.x;
  o.y = g0 * a.y + g1 * b.y;
  o.z = g0 * a.z + g1 * b.z;
  o.w = g0 * a.w + g1 * b.w;
  ((float4*)(out + (size_t)t * DDIM))[tid] = o;
}

extern "C" void kernel_launch(void* const* d_in, const int* in_sizes, int n_in,
                              void* d_out, int out_size, void* d_ws, size_t ws_size,
                              hipStream_t stream)
{
  const float* x     = (const float*)d_in[0];
  const float* noise = (const float*)d_in[1];
  const float* Wr    = (const float*)d_in[2];
  const float* br    = (const float*)d_in[3];
  const float* Wn    = (const float*)d_in[4];
  const float* bn    = (const float*)d_in[5];
  const float* W1    = (const float*)d_in[6];
  const float* b1    = (const float*)d_in[7];
  const float* W2    = (const float*)d_in[8];
  const float* b2    = (const float*)d_in[9];
  float* out = (float*)d_out;

  char* ws = (char*)d_ws;
  size_t o = 0;
  auto alloc = [&](size_t sz) {
    void* p = ws + o;
    o = (o + sz + 255) & ~(size_t)255;
    return p;
  };
  ushort* WT1 = (ushort*)alloc((size_t)NE * FDIM * DDIM * 2);      // 64 MB
  ushort* WT2 = (ushort*)alloc((size_t)NE * DDIM * FDIM * 2);      // 64 MB
  ushort* XG  = (ushort*)alloc((size_t)(NPAIR + 128) * DDIM * 2);  // 16 MB
  ushort* H   = (ushort*)alloc((size_t)(NPAIR + 128) * FDIM * 2);  // 65 MB
  float*  EO  = (float*)alloc((size_t)(NPAIR + 128) * DDIM * 4);   // 33 MB
  int*    TOK_TOP  = (int*)alloc(T_TOK * 2 * 4);
  float*  TOK_GATE = (float*)alloc(T_TOK * 2 * 4);
  int*    TOK_PPOS = (int*)alloc(T_TOK * 2 * 4);
  int*    PAIR_TOK = (int*)alloc(NPAIR * 4);
  int*    CNT = (int*)alloc(64);
  int*    OFF = (int*)alloc(64);
  int*    CUR = (int*)alloc(64);

  hipMemsetAsync(CNT, 0, 64, stream);
  router_kernel<<<T_TOK / 4, 256, 0, stream>>>(x, noise, Wr, br, Wn, bn,
                                               TOK_TOP, TOK_GATE, CNT);
  scan_kernel<<<1, 64, 0, stream>>>(CNT, OFF, CUR);
  scatter_kernel<<<T_TOK / 256, 256, 0, stream>>>(TOK_TOP, TOK_GATE, CUR,
                                                  PAIR_TOK, TOK_PPOS);
  gather_x_kernel<<<NPAIR, 256, 0, stream>>>(x, PAIR_TOK, XG);
  transpose_bf_kernel<<<dim3(FDIM / 32, DDIM / 32, NE), 256, 0, stream>>>(W1, WT1, DDIM, FDIM);
  transpose_bf_kernel<<<dim3(DDIM / 32, FDIM / 32, NE), 256, 0, stream>>>(W2, WT2, FDIM, DDIM);
  gemm_kernel<DDIM, 32, 0><<<dim3(32, 512), 256, 0, stream>>>(XG, WT1, OFF, b1, H, nullptr);
  gemm_kernel<FDIM, 8, 1><<<dim3(8, 512), 256, 0, stream>>>(H, WT2, OFF, b2, nullptr, EO);
  combine_kernel<<<T_TOK, 256, 0, stream>>>(EO, TOK_PPOS, TOK_GATE, out);
}